// Round 21
// baseline (142.281 us; speedup 1.0000x reference)
//
#include <hip/hip_runtime.h>

#define BB   256
#define NIN  1152
#define OO   10
#define IL   8
#define OL   16
#define ROW  160
#define EPSQ 1e-7f
#define NCHP 144          // psum chunks = 36 blocks.y x 4 waves (8 n each)

typedef short s16x8 __attribute__((ext_vector_type(8)));
typedef float f32x4 __attribute__((ext_vector_type(4)));

__device__ __forceinline__ unsigned short f2bf(float f) {
    unsigned u = __builtin_bit_cast(unsigned, f);
    u += 0x7FFFu + ((u >> 16) & 1u);   // RNE
    return (unsigned short)(u >> 16);
}

// K1: fused prep (verified r9/r20 bodies, one launch).
// blocks [0,1152): xp[n*256+b][i] = bf16(x[b][n][i])
// blocks [1152,1872): wp[(n*10+o)*16+l][i] = bf16(w[n][o][i][l])
__global__ __launch_bounds__(256) void caps_prep(
    const float* __restrict__ x, const float* __restrict__ w,
    short* __restrict__ xp, short* __restrict__ wp)
{
    const int bid = blockIdx.x;
    if (bid < 1152) {
        const int id = bid * 256 + threadIdx.x;       // < 256*1152
        const int n  = id % NIN;
        const int b  = id / NIN;
        const float4* src = reinterpret_cast<const float4*>(x + (size_t)id * IL);
        const float4 a = src[0], c = src[1];
        union { s16x8 v; unsigned short h[8]; } pk;
        pk.h[0] = f2bf(a.x); pk.h[1] = f2bf(a.y); pk.h[2] = f2bf(a.z); pk.h[3] = f2bf(a.w);
        pk.h[4] = f2bf(c.x); pk.h[5] = f2bf(c.y); pk.h[6] = f2bf(c.z); pk.h[7] = f2bf(c.w);
        *reinterpret_cast<s16x8*>(xp + ((size_t)n * BB + b) * 8) = pk.v;
    } else {
        const int id = (bid - 1152) * 256 + threadIdx.x;  // < 1152*160
        const int l  = id & 15;
        const int no = id >> 4;
        const float* src = w + (size_t)no * (IL * OL) + l;
        union { s16x8 v; unsigned short h[8]; } pk;
        #pragma unroll
        for (int i = 0; i < IL; ++i)
            pk.h[i] = f2bf(src[i * OL]);
        *reinterpret_cast<s16x8*>(wp + (size_t)id * 8) = pk.v;
    }
}

// K2: one routing pass, u recomputed per n via MFMA with SWAPPED operands:
// acc[o] = mfma(A=W_frag, B=X_frag): C col=lane&15=b, row=(lane>>4)*4+r=k.
// -> k is (lg,r)-local: dot over k = 4 in-lane FMA + xor16 + xor32 (2 shfl);
// softmax over o in-lane; c*u accumulation in-lane. (Round 9's failure was
// the unswapped layout: k across 16 lanes = 160 shfl per n.)
// K=8 real of 32: only B (x-frag) needs zeroing for lg>0 (A*0=0).
// Grid (16 b-tiles, 36); 256 thr = 4 waves; wave = 8 n; psum chunk = by*4+wv.
template<int ITER>
__global__ __launch_bounds__(256, 1) void caps_pass(
    const short* __restrict__ xp, const short* __restrict__ wp,
    const float* __restrict__ vin, float* __restrict__ psum)
{
    const int t   = threadIdx.x;
    const int l   = t & 63;
    const int wv  = t >> 6;
    const int l15 = l & 15;
    const int lg  = l >> 4;
    const int b0  = blockIdx.x * 16;
    const int nb  = blockIdx.y;
    const int n0  = nb * 32 + wv * 8;
    const int chunk = nb * 4 + wv;
    const bool lz = (lg == 0);

    const s16x8 zf = (s16x8){0, 0, 0, 0, 0, 0, 0, 0};

    f32x4 sp[OO];
    #pragma unroll
    for (int o = 0; o < OO; ++o) sp[o] = (f32x4){0.f, 0.f, 0.f, 0.f};

    f32x4 vreg[OO];
    if (ITER) {
        #pragma unroll
        for (int o = 0; o < OO; ++o)
            vreg[o] = *reinterpret_cast<const f32x4*>(
                vin + (size_t)(b0 + l15) * ROW + o * OL + lg * 4);
    }

    for (int nn = 0; nn < 8; ++nn) {
        const int n = n0 + nn;
        // B = x-frag: col=b0+l15, k-slots lg*8..+7 (real only for lg==0)
        const s16x8 Bx0 = *reinterpret_cast<const s16x8*>(
            xp + ((size_t)n * BB + b0 + l15) * 8);
        const s16x8 Bx = lz ? Bx0 : zf;

        // A = w-frags: row=k_out=l15, same slots; lg>0 lanes multiply by 0
        const short* wbase = wp + ((size_t)n * OO * 16 + l15) * 8;
        s16x8 A[OO];
        #pragma unroll
        for (int o = 0; o < OO; ++o)
            A[o] = *reinterpret_cast<const s16x8*>(wbase + o * 128);

        f32x4 acc[OO];
        #pragma unroll
        for (int o = 0; o < OO; ++o)
            acc[o] = __builtin_amdgcn_mfma_f32_16x16x32_bf16(
                A[o], Bx, (f32x4){0.f, 0.f, 0.f, 0.f}, 0, 0, 0);
        // acc[o][r] = u_hat[b0+l15][n][o][k = lg*4+r]

        if (ITER == 0) {
            #pragma unroll
            for (int o = 0; o < OO; ++o) {
                sp[o][0] += acc[o][0]; sp[o][1] += acc[o][1];
                sp[o][2] += acc[o][2]; sp[o][3] += acc[o][3];
            }
        } else {
            float d[OO];
            #pragma unroll
            for (int o = 0; o < OO; ++o) {
                float dd = acc[o][0] * vreg[o][0];
                dd = fmaf(acc[o][1], vreg[o][1], dd);
                dd = fmaf(acc[o][2], vreg[o][2], dd);
                dd = fmaf(acc[o][3], vreg[o][3], dd);
                dd += __shfl_xor(dd, 16);
                dd += __shfl_xor(dd, 32);
                d[o] = dd;
            }
            float mx = d[0];
            #pragma unroll
            for (int o = 1; o < OO; ++o) mx = fmaxf(mx, d[o]);
            float e[OO], se = 0.f;
            #pragma unroll
            for (int o = 0; o < OO; ++o) { e[o] = __expf(d[o] - mx); se += e[o]; }
            const float rinv = 1.f / se;
            #pragma unroll
            for (int o = 0; o < OO; ++o) {
                const float c = e[o] * rinv;
                sp[o][0] = fmaf(c, acc[o][0], sp[o][0]);
                sp[o][1] = fmaf(c, acc[o][1], sp[o][1]);
                sp[o][2] = fmaf(c, acc[o][2], sp[o][2]);
                sp[o][3] = fmaf(c, acc[o][3], sp[o][3]);
            }
        }
    }

    float* pb = psum + ((size_t)chunk * BB + b0 + l15) * ROW + lg * 4;
    #pragma unroll
    for (int o = 0; o < OO; ++o)
        *reinterpret_cast<f32x4*>(pb + o * OL) = sp[o];
}

// K3: sum psum chunks (144) + bias, squash; optional prevAdd. (verified shape)
__global__ __launch_bounds__(192) void caps_finish(
    const float* __restrict__ psum, const float* __restrict__ bias,
    const float* __restrict__ prevAdd, float* __restrict__ outv, float scale)
{
    const int t = threadIdx.x;
    if (t >= ROW) return;
    const int b = blockIdx.x;

    float s0 = 0.f, s1 = 0.f, s2 = 0.f, s3 = 0.f;
    const float* pt = psum + (size_t)b * ROW + t;
    for (int ch = 0; ch < NCHP; ch += 4) {
        s0 += pt[(size_t)(ch + 0) * BB * ROW];
        s1 += pt[(size_t)(ch + 1) * BB * ROW];
        s2 += pt[(size_t)(ch + 2) * BB * ROW];
        s3 += pt[(size_t)(ch + 3) * BB * ROW];
    }
    const float s = scale * ((s0 + s1) + (s2 + s3)) + bias[t];

    float d = s * s;
    d += __shfl_xor(d, 1, 16);
    d += __shfl_xor(d, 2, 16);
    d += __shfl_xor(d, 4, 16);
    d += __shfl_xor(d, 8, 16);
    const float f = d / ((1.f + d) * sqrtf(d + EPSQ));
    float v = f * s;
    if (prevAdd) v += prevAdd[(size_t)b * ROW + t];
    outv[(size_t)b * ROW + t] = v;
}

extern "C" void kernel_launch(void* const* d_in, const int* in_sizes, int n_in,
                              void* d_out, int out_size, void* d_ws, size_t ws_size,
                              hipStream_t stream) {
    const float* x    = (const float*)d_in[0]; // (B, NIN, 8, 1)
    const float* w    = (const float*)d_in[1]; // (1, NIN, O, 8, 16)
    const float* bias = (const float*)d_in[2]; // (1, 1, O, 16, 1)
    float* out = (float*)d_out;                // (B, 1, O, 16, 1)

    short* xp = (short*)d_ws;                                  // 4.7 MB
    short* wp = xp + (size_t)NIN * BB * 8;                     // 3.0 MB
    float* psum = (float*)(wp + (size_t)NIN * OO * 16 * 8);    // 23.6 MB
    float* v0   = psum + (size_t)NCHP * BB * ROW;              // 160 KB
    float* vsb  = v0 + (size_t)BB * ROW;                       // 160 KB

    const dim3 pg(BB / 16, 36);

    caps_prep<<<1872, 256, 0, stream>>>(x, w, xp, wp);
    // iter0: uniform c (scale 0.1) -> v0
    caps_pass<0><<<pg, 256, 0, stream>>>(xp, wp, nullptr, psum);
    caps_finish<<<BB, 192, 0, stream>>>(psum, bias, nullptr, v0, 0.1f);
    // iter1: c = softmax(u.v0) -> vsb = v1 + v0
    caps_pass<1><<<pg, 256, 0, stream>>>(xp, wp, v0, psum);
    caps_finish<<<BB, 192, 0, stream>>>(psum, bias, v0, vsb, 1.0f);
    // iter2: c = softmax(u.(v0+v1)) -> out
    caps_pass<2><<<pg, 256, 0, stream>>>(xp, wp, vsb, psum);
    caps_finish<<<BB, 192, 0, stream>>>(psum, bias, nullptr, out, 1.0f);
}

// Round 22
// 87.422 us; speedup vs baseline: 1.6275x; 1.6275x over previous
//
#include <hip/hip_runtime.h>
#include <hip/hip_bf16.h>

#define BB   256
#define NIN  1152
#define OO   10
#define IL   8
#define OL   16
#define ROW  (OO*OL)      // 160
#define EPSQ 1e-7f
#define NT   4            // n-tile per build block
#define BT   32           // b-tile per build block
#define KSP  8            // gemm0 K-splits (144 n each)

typedef unsigned short ushx8 __attribute__((ext_vector_type(8)));
typedef short s16x8 __attribute__((ext_vector_type(8)));
typedef float f32x4 __attribute__((ext_vector_type(4)));

__device__ __forceinline__ float bf2f(unsigned short h) {
    unsigned u = ((unsigned)h) << 16;
    return __builtin_bit_cast(float, u);
}
__device__ __forceinline__ unsigned short f2bf(float f) {
    unsigned u = __builtin_bit_cast(unsigned, f);
    u += 0x7FFFu + ((u >> 16) & 1u);   // RNE
    return (unsigned short)(u >> 16);
}

// K1: build u_hat[b][n][o*16+k] in bf16. VERIFIED round-13/14 (~9us).
__global__ __launch_bounds__(160) void caps_build(
    const float* __restrict__ x, const float* __restrict__ w,
    unsigned short* __restrict__ u)
{
    __shared__ float4 wl4[NT][321];
    __shared__ float4 xl4[BT * 8];
    const int t  = threadIdx.x;
    const int n0 = blockIdx.x * NT;
    const int b0 = blockIdx.y * BT;

    const float4* wg = reinterpret_cast<const float4*>(w) + (size_t)n0 * 320;
    #pragma unroll
    for (int jj = 0; jj < 8; ++jj) {
        const int j   = t + jj * 160;
        const int row = j / 320;
        const int lin = j - row * 320;
        const int o   = lin >> 5;
        const int rem = lin & 31;
        const int i   = rem >> 2;
        const int kh  = rem & 3;
        wl4[row][(o << 5) | ((i ^ (o & 1)) << 2) | kh] = wg[j];
    }
    const float4* xg = reinterpret_cast<const float4*>(x);
    {
        int j = t;
        xl4[j] = xg[((size_t)(b0 + (j >> 3)) * NIN + n0) * 2 + (j & 7)];
        j = t + 160;
        if (j < BT * 8)
            xl4[j] = xg[((size_t)(b0 + (j >> 3)) * NIN + n0) * 2 + (j & 7)];
    }
    __syncthreads();

    const int nl = t / 40;
    const int r  = t - nl * 40;
    const int hh = r / 20;
    const int s  = r - hh * 20;
    const int o  = s >> 1;
    const int k8 = s & 1;
    const int p  = o & 1;
    const float4* wbase = &wl4[nl][(o << 5) | (k8 << 1)];
    const float4* xbase = &xl4[(hh * 16) * 8 + nl * 2];
    unsigned short* ub = u + ((size_t)(b0 + hh * 16) * NIN + n0 + nl) * ROW
                           + o * OL + k8 * 8;
    const size_t ustride = (size_t)NIN * ROW;

    for (int bl = 0; bl < 16; bl += 4) {
        float xv[4][IL];
        #pragma unroll
        for (int bb = 0; bb < 4; ++bb) {
            const float4 x0 = xbase[(bl + bb) * 8];
            const float4 x1 = xbase[(bl + bb) * 8 + 1];
            xv[bb][0] = x0.x; xv[bb][1] = x0.y; xv[bb][2] = x0.z; xv[bb][3] = x0.w;
            xv[bb][4] = x1.x; xv[bb][5] = x1.y; xv[bb][6] = x1.z; xv[bb][7] = x1.w;
        }

        float acc[4][8];
        #pragma unroll
        for (int bb = 0; bb < 4; ++bb)
            #pragma unroll
            for (int j = 0; j < 8; ++j) acc[bb][j] = 0.f;

        #pragma unroll
        for (int i = 0; i < IL; ++i) {
            const float4 wlo = wbase[(i ^ p) << 2];
            const float4 whi = wbase[((i ^ p) << 2) | 1];
            const float wv[8] = {wlo.x, wlo.y, wlo.z, wlo.w, whi.x, whi.y, whi.z, whi.w};
            #pragma unroll
            for (int bb = 0; bb < 4; ++bb)
                #pragma unroll
                for (int j = 0; j < 8; ++j)
                    acc[bb][j] = fmaf(wv[j], xv[bb][i], acc[bb][j]);
        }

        #pragma unroll
        for (int bb = 0; bb < 4; ++bb) {
            union { ushx8 v; __hip_bfloat162 h[4]; } pk;
            #pragma unroll
            for (int j = 0; j < 4; ++j)
                pk.h[j] = __float22bfloat162_rn(make_float2(acc[bb][2*j], acc[bb][2*j+1]));
            *reinterpret_cast<ushx8*>(ub + (size_t)(bl + bb) * ustride) = pk.v;
        }
    }
}

// K2: MFMA GEMM for iter0's reduction, DIRECT from fp32 x and w (no prep):
// psum[ks][b][o*16+k] = sum over the split's 144 n of u_hat. Same fragment /
// C-layout convention as round-20's verified gemm0 (A lane l15 = b-row, slot
// group lg; B lane l15 = col; C row = lg*4+r, col = l15). Per k-step (4 n):
// A = 2 float4 x-loads -> bf16; B = 8 strided w-loads -> bf16; 1 MFMA into a
// single f32x4 accumulator (tiny VGPR, nothing for the allocator to strip).
// Grid (40, 8): wave = one (b-tile, o) output tile, 36 k-steps.
__global__ __launch_bounds__(256) void caps_gemm0(
    const float* __restrict__ x, const float* __restrict__ w,
    float* __restrict__ psum)
{
    const int t   = threadIdx.x;
    const int l   = t & 63;
    const int wv  = t >> 6;
    const int idx = blockIdx.x * 4 + wv;   // 0..159
    const int bt  = idx / 10;
    const int ct  = idx - bt * 10;         // = o
    const int ks  = blockIdx.y;            // 0..7
    const int l15 = l & 15, lg = l >> 4;
    const int b   = bt * 16 + l15;

    f32x4 acc = (f32x4){0.f, 0.f, 0.f, 0.f};

    #pragma unroll 4
    for (int kstep = 0; kstep < 36; ++kstep) {
        const int n = ks * 144 + kstep * 4 + lg;

        // A-frag: x[b][n][0..7] (8 consecutive fp32) -> bf16
        const float* xpn = x + ((size_t)b * NIN + n) * 8;
        const float4 xa = *reinterpret_cast<const float4*>(xpn);
        const float4 xc = *reinterpret_cast<const float4*>(xpn + 4);
        union { s16x8 v; unsigned short h[8]; } A;
        A.h[0] = f2bf(xa.x); A.h[1] = f2bf(xa.y); A.h[2] = f2bf(xa.z); A.h[3] = f2bf(xa.w);
        A.h[4] = f2bf(xc.x); A.h[5] = f2bf(xc.y); A.h[6] = f2bf(xc.z); A.h[7] = f2bf(xc.w);

        // B-frag: w[n][ct][i][l15], i = 0..7 (stride 16 fp32) -> bf16
        const float* wb = w + (((size_t)n * OO + ct) * IL) * OL + l15;
        union { s16x8 v; unsigned short h[8]; } B;
        #pragma unroll
        for (int i = 0; i < IL; ++i) B.h[i] = f2bf(wb[i * OL]);

        acc = __builtin_amdgcn_mfma_f32_16x16x32_bf16(A.v, B.v, acc, 0, 0, 0);
    }

    float* pb = psum + ((size_t)ks * BB + bt * 16 + lg * 4) * ROW + ct * OL + l15;
    #pragma unroll
    for (int r = 0; r < 4; ++r)
        pb[(size_t)r * ROW] = acc[r];
}

// K3: routing iterations 1,2 fused (verified r15..r20 body). Prologue now
// sums the 8 psum splits + bias and squashes inline (verified squash math),
// eliminating the separate squash0 kernel and its launch gap.
__global__ __launch_bounds__(768) void caps_route2(
    const unsigned short* __restrict__ u, const float* __restrict__ bias,
    const float* __restrict__ psum, float* __restrict__ outv)
{
    __shared__ float lds[12][ROW];
    __shared__ float vbuf[ROW];
    const int t  = threadIdx.x;
    const int q  = t & 3;
    const int g  = t >> 2;     // 0..191
    const int wv = t >> 6;     // 0..11
    const int b  = blockIdx.x;
    const unsigned short* ub = u + (size_t)b * NIN * ROW;

    float bsv = 0.f;
    float vprev = 0.f;
    if (t < ROW) {
        bsv = bias[t];
        // inline iter0 finish: sum 8 K-splits, *0.1 + bias, squash
        const float* pt = psum + (size_t)b * ROW + t;
        float s0 = pt[0];
        #pragma unroll
        for (int ks = 1; ks < KSP; ++ks) s0 += pt[(size_t)ks * BB * ROW];
        const float s = 0.1f * s0 + bsv;

        float d = s * s;
        d += __shfl_xor(d, 1, 16);
        d += __shfl_xor(d, 2, 16);
        d += __shfl_xor(d, 4, 16);
        d += __shfl_xor(d, 8, 16);
        const float f = d / ((1.f + d) * sqrtf(d + EPSQ));
        const float v = f * s;
        vbuf[t] = v;
        vprev = v;
    }
    __syncthreads();

    #pragma unroll
    for (int iter = 1; iter < 3; ++iter) {
        float sp[5][8];
        #pragma unroll
        for (int j = 0; j < 5; ++j)
            #pragma unroll
            for (int e = 0; e < 8; ++e) sp[j][e] = 0.f;

        float vs[5][8];
        #pragma unroll
        for (int j = 0; j < 5; ++j) {
            #pragma unroll
            for (int e = 0; e < 8; ++e) vs[j][e] = vbuf[(q + 4 * j) * 8 + e];
        }

        for (int m = 0; m < 6; ++m) {
            const unsigned short* un = ub + (size_t)(g + m * 192) * ROW;
            float uf[5][8];
            #pragma unroll
            for (int j = 0; j < 5; ++j) {
                const ushx8 raw = *reinterpret_cast<const ushx8*>(un + (q + 4 * j) * 8);
                #pragma unroll
                for (int e = 0; e < 8; ++e) uf[j][e] = bf2f(raw[e]);
            }

            // own-parity dots (half-k), combine halves, then swap parity
            float d[5], dd[5];
            #pragma unroll
            for (int j = 0; j < 5; ++j) {
                float acc = uf[j][0] * vs[j][0];
                #pragma unroll
                for (int e = 1; e < 8; ++e) acc = fmaf(uf[j][e], vs[j][e], acc);
                acc += __shfl_xor(acc, 1, 4);   // h=0 + h=1 -> full 16-k dot
                d[j] = acc;
            }
            #pragma unroll
            for (int j = 0; j < 5; ++j) dd[j] = __shfl_xor(d[j], 2, 4);

            float mx = fmaxf(d[0], dd[0]);
            #pragma unroll
            for (int j = 1; j < 5; ++j) mx = fmaxf(mx, fmaxf(d[j], dd[j]));
            float se = 0.f, e_[5];
            #pragma unroll
            for (int j = 0; j < 5; ++j) {
                e_[j] = __expf(d[j] - mx);
                se += e_[j] + __expf(dd[j] - mx);
            }
            const float rr = 1.f / se;
            #pragma unroll
            for (int j = 0; j < 5; ++j) {
                const float c = e_[j] * rr;
                #pragma unroll
                for (int e = 0; e < 8; ++e)
                    sp[j][e] = fmaf(c, uf[j][e], sp[j][e]);
            }
        }

        // butterfly over the 16 groups of each wave (masks preserve q)
        #pragma unroll
        for (int j = 0; j < 5; ++j)
            #pragma unroll
            for (int e = 0; e < 8; ++e) {
                #pragma unroll
                for (int msk = 4; msk <= 32; msk <<= 1)
                    sp[j][e] += __shfl_xor(sp[j][e], msk);
            }
        if ((t & 63) < 4) {
            #pragma unroll
            for (int j = 0; j < 5; ++j)
                #pragma unroll
                for (int e = 0; e < 8; ++e)
                    lds[wv][(q + 4 * j) * 8 + e] = sp[j][e];
        }
        __syncthreads();

        if (t < ROW) {
            float ssum = 0.f;
            #pragma unroll
            for (int wvi = 0; wvi < 12; ++wvi) ssum += lds[wvi][t];
            const float sv = ssum + bsv;

            float dq = sv * sv;
            dq += __shfl_xor(dq, 1, 16);
            dq += __shfl_xor(dq, 2, 16);
            dq += __shfl_xor(dq, 4, 16);
            dq += __shfl_xor(dq, 8, 16);
            const float f = dq / ((1.f + dq) * sqrtf(dq + EPSQ));
            const float v = f * sv;

            if (iter == 1) { vbuf[t] = v + vprev; }
            else           { outv[(size_t)b * ROW + t] = v; }
        }
        __syncthreads();
    }
}

extern "C" void kernel_launch(void* const* d_in, const int* in_sizes, int n_in,
                              void* d_out, int out_size, void* d_ws, size_t ws_size,
                              hipStream_t stream) {
    const float* x    = (const float*)d_in[0]; // (B, NIN, 8, 1)
    const float* w    = (const float*)d_in[1]; // (1, NIN, O, 8, 16)
    const float* bias = (const float*)d_in[2]; // (1, 1, O, 16, 1)
    float* out = (float*)d_out;                // (B, 1, O, 16, 1)

    unsigned short* u = (unsigned short*)d_ws;                        // 94.4 MB
    float* psum = (float*)((char*)d_ws + (size_t)BB * NIN * ROW * 2); // 1.3 MB

    caps_build<<<dim3(NIN / NT, BB / BT), 160, 0, stream>>>(x, w, u);
    caps_gemm0<<<dim3(40, KSP), 256, 0, stream>>>(x, w, psum);
    caps_route2<<<BB, 768, 0, stream>>>(u, bias, psum, out);
}